// Round 1
// baseline (549.810 us; speedup 1.0000x reference)
//
#include <hip/hip_runtime.h>

#define N_NODES 10000
#define N_EDGES 320000

// ---------------------------------------------------------------------------
// Graph preprocessing: deg/dinv + CSR-by-destination build
// ---------------------------------------------------------------------------

__global__ __launch_bounds__(256) void init_kernel(float* deg, int* counts, int* cursor, int n) {
    int i = blockIdx.x * 256 + threadIdx.x;
    if (i < n) { deg[i] = 1.0f; counts[i] = 0; cursor[i] = 0; }  // self-loop weight 1
}

__global__ __launch_bounds__(256) void deg_count_kernel(const int* __restrict__ col,
                                                        const float* __restrict__ ew,
                                                        float* __restrict__ deg,
                                                        int* __restrict__ counts, int e) {
    int i = blockIdx.x * 256 + threadIdx.x;
    if (i < e) {
        int c = col[i];
        atomicAdd(deg + c, ew[i]);
        atomicAdd(counts + c, 1);
    }
}

__global__ __launch_bounds__(1024) void scan_kernel(const int* __restrict__ counts,
                                                    int* __restrict__ ptr, int n) {
    __shared__ int buf[1024];
    __shared__ int carry_s;
    if (threadIdx.x == 0) carry_s = 0;
    __syncthreads();
    for (int base = 0; base < n; base += 1024) {
        int i = base + (int)threadIdx.x;
        int v = (i < n) ? counts[i] : 0;
        buf[threadIdx.x] = v;
        __syncthreads();
        int x = v;
        for (int off = 1; off < 1024; off <<= 1) {
            int t = 0;
            if ((int)threadIdx.x >= off) t = buf[threadIdx.x - off];
            __syncthreads();
            x += t;
            buf[threadIdx.x] = x;
            __syncthreads();
        }
        int carry = carry_s;
        if (i < n) ptr[i] = carry + x - v;  // exclusive scan
        __syncthreads();
        if (threadIdx.x == 1023) carry_s = carry + x;
        __syncthreads();
    }
    if (threadIdx.x == 0) ptr[n] = carry_s;
}

__global__ __launch_bounds__(256) void dinv_kernel(const float* __restrict__ deg,
                                                   float* __restrict__ dinv, int n) {
    int i = blockIdx.x * 256 + threadIdx.x;
    if (i < n) {
        float d = deg[i];
        dinv[i] = (d > 0.0f) ? rsqrtf(d) : 0.0f;
    }
}

__global__ __launch_bounds__(256) void scatter_kernel(const int* __restrict__ row,
                                                      const int* __restrict__ col,
                                                      const float* __restrict__ ew,
                                                      const float* __restrict__ dinv,
                                                      const int* __restrict__ ptr,
                                                      int* __restrict__ cursor,
                                                      int* __restrict__ csr_src,
                                                      float* __restrict__ csr_w, int e) {
    int i = blockIdx.x * 256 + threadIdx.x;
    if (i < e) {
        int c = col[i], r = row[i];
        int pos = ptr[c] + atomicAdd(cursor + c, 1);
        csr_src[pos] = r;
        csr_w[pos] = dinv[r] * ew[i] * dinv[c];
    }
}

// ---------------------------------------------------------------------------
// fp32 GEMM: C[M,N] = A[M,K] @ B[K,N].  64x64 tile, 256 threads, 4x4/thread.
// Requires K % 16 == 0, N % 64 == 0 (true for layers 1 & 2).
// ---------------------------------------------------------------------------

__global__ __launch_bounds__(256) void gemm64_kernel(const float* __restrict__ A,
                                                     const float* __restrict__ B,
                                                     float* __restrict__ C,
                                                     int M, int K, int N) {
    __shared__ float As[16][65];   // +1 pad: breaks 4-way store conflict
    __shared__ float Bs[16][64];
    int t = threadIdx.x;
    int bm = blockIdx.y * 64;
    int bn = blockIdx.x * 64;
    int tx = t & 15, ty = t >> 4;
    float acc[4][4] = {};

    int am = t >> 2;            // 0..63 : A tile row
    int ak = (t & 3) * 4;       // 0,4,8,12 : A tile k quad
    int bk = t >> 4;            // 0..15 : B tile k row
    int bn4 = (t & 15) * 4;     // B tile col quad

    for (int k0 = 0; k0 < K; k0 += 16) {
        float4 av = make_float4(0.f, 0.f, 0.f, 0.f);
        int arow = bm + am;
        if (arow < M) av = *(const float4*)(A + (size_t)arow * K + k0 + ak);
        As[ak + 0][am] = av.x;
        As[ak + 1][am] = av.y;
        As[ak + 2][am] = av.z;
        As[ak + 3][am] = av.w;
        float4 bv = *(const float4*)(B + (size_t)(k0 + bk) * N + bn + bn4);
        *(float4*)(&Bs[bk][bn4]) = bv;
        __syncthreads();
#pragma unroll
        for (int k = 0; k < 16; ++k) {
            float a0 = As[k][ty * 4 + 0], a1 = As[k][ty * 4 + 1];
            float a2 = As[k][ty * 4 + 2], a3 = As[k][ty * 4 + 3];
            float b0 = Bs[k][tx * 4 + 0], b1 = Bs[k][tx * 4 + 1];
            float b2 = Bs[k][tx * 4 + 2], b3 = Bs[k][tx * 4 + 3];
            acc[0][0] += a0 * b0; acc[0][1] += a0 * b1; acc[0][2] += a0 * b2; acc[0][3] += a0 * b3;
            acc[1][0] += a1 * b0; acc[1][1] += a1 * b1; acc[1][2] += a1 * b2; acc[1][3] += a1 * b3;
            acc[2][0] += a2 * b0; acc[2][1] += a2 * b1; acc[2][2] += a2 * b2; acc[2][3] += a2 * b3;
            acc[3][0] += a3 * b0; acc[3][1] += a3 * b1; acc[3][2] += a3 * b2; acc[3][3] += a3 * b3;
        }
        __syncthreads();
    }
#pragma unroll
    for (int i = 0; i < 4; ++i) {
        int m = bm + ty * 4 + i;
        if (m < M) {
            float4 v = make_float4(acc[i][0], acc[i][1], acc[i][2], acc[i][3]);
            *(float4*)(C + (size_t)m * N + bn + tx * 4) = v;
        }
    }
}

// GEMM for layer 3: N=8, K=768.  One 64-lane wave per output row.
__global__ __launch_bounds__(64) void gemm_n8_kernel(const float* __restrict__ A,
                                                     const float* __restrict__ B,
                                                     float* __restrict__ C, int K) {
    int m = blockIdx.x;
    int lane = threadIdx.x;
    const float* a = A + (size_t)m * K;
    float acc[8] = {};
    for (int k = lane; k < K; k += 64) {
        float av = a[k];
        float4 b0 = *(const float4*)(B + (size_t)k * 8);
        float4 b1 = *(const float4*)(B + (size_t)k * 8 + 4);
        acc[0] += av * b0.x; acc[1] += av * b0.y; acc[2] += av * b0.z; acc[3] += av * b0.w;
        acc[4] += av * b1.x; acc[5] += av * b1.y; acc[6] += av * b1.z; acc[7] += av * b1.w;
    }
#pragma unroll
    for (int off = 32; off > 0; off >>= 1) {
#pragma unroll
        for (int i = 0; i < 8; ++i) acc[i] += __shfl_down(acc[i], off);
    }
    if (lane == 0) {
#pragma unroll
        for (int i = 0; i < 8; ++i) C[(size_t)m * 8 + i] = acc[i];
    }
}

// ---------------------------------------------------------------------------
// Aggregation: out[n,f] = dinv[n]^2*xw[n,f] + sum_{in-edges} w*xw[src,f] + b[f]
// One block of 64 threads per (node, 256-feature chunk); float4 per thread.
// ---------------------------------------------------------------------------

__global__ __launch_bounds__(64) void agg_kernel(const float* __restrict__ xw,
                                                 const int* __restrict__ ptr,
                                                 const int* __restrict__ csr_src,
                                                 const float* __restrict__ csr_w,
                                                 const float* __restrict__ dinv,
                                                 const float* __restrict__ bias,
                                                 float* __restrict__ out,
                                                 int fout, int relu) {
    int node = blockIdx.x;
    int f0 = blockIdx.y * 256 + threadIdx.x * 4;
    if (f0 >= fout) return;
    float di = dinv[node];
    float si = di * di;
    float4 v = *(const float4*)(xw + (size_t)node * fout + f0);
    float4 acc = make_float4(si * v.x, si * v.y, si * v.z, si * v.w);
    int s = ptr[node], e = ptr[node + 1];
    for (int j = s; j < e; ++j) {
        int src = csr_src[j];
        float w = csr_w[j];
        float4 g = *(const float4*)(xw + (size_t)src * fout + f0);
        acc.x += w * g.x; acc.y += w * g.y; acc.z += w * g.z; acc.w += w * g.w;
    }
    float4 b = *(const float4*)(bias + f0);
    acc.x += b.x; acc.y += b.y; acc.z += b.z; acc.w += b.w;
    if (relu) {
        acc.x = fmaxf(acc.x, 0.f); acc.y = fmaxf(acc.y, 0.f);
        acc.z = fmaxf(acc.z, 0.f); acc.w = fmaxf(acc.w, 0.f);
    }
    *(float4*)(out + (size_t)node * fout + f0) = acc;
}

// Aggregation for fout=8 (final layer): one wave per node, lanes split edges.
__global__ __launch_bounds__(64) void agg8_kernel(const float* __restrict__ xw,
                                                  const int* __restrict__ ptr,
                                                  const int* __restrict__ csr_src,
                                                  const float* __restrict__ csr_w,
                                                  const float* __restrict__ dinv,
                                                  const float* __restrict__ bias,
                                                  float* __restrict__ out) {
    int node = blockIdx.x;
    int lane = threadIdx.x;
    float acc[8] = {};
    int s = ptr[node], e = ptr[node + 1];
    for (int j = s + lane; j < e; j += 64) {
        int src = csr_src[j];
        float w = csr_w[j];
        float4 g0 = *(const float4*)(xw + (size_t)src * 8);
        float4 g1 = *(const float4*)(xw + (size_t)src * 8 + 4);
        acc[0] += w * g0.x; acc[1] += w * g0.y; acc[2] += w * g0.z; acc[3] += w * g0.w;
        acc[4] += w * g1.x; acc[5] += w * g1.y; acc[6] += w * g1.z; acc[7] += w * g1.w;
    }
#pragma unroll
    for (int off = 32; off > 0; off >>= 1) {
#pragma unroll
        for (int i = 0; i < 8; ++i) acc[i] += __shfl_down(acc[i], off);
    }
    if (lane == 0) {
        float di = dinv[node];
        float si = di * di;
#pragma unroll
        for (int i = 0; i < 8; ++i)
            out[(size_t)node * 8 + i] = acc[i] + si * xw[(size_t)node * 8 + i] + bias[i];
    }
}

// ---------------------------------------------------------------------------

extern "C" void kernel_launch(void* const* d_in, const int* in_sizes, int n_in,
                              void* d_out, int out_size, void* d_ws, size_t ws_size,
                              hipStream_t stream) {
    const int N = N_NODES, E = N_EDGES;
    const float* x   = (const float*)d_in[0];
    const int*   ei  = (const int*)d_in[1];   // [2, E] (row=source, col=target)
    const float* ew  = (const float*)d_in[2];
    const float* W1  = (const float*)d_in[3];
    const float* b1  = (const float*)d_in[4];
    const float* W2  = (const float*)d_in[5];
    const float* b2  = (const float*)d_in[6];
    const float* W3  = (const float*)d_in[7];
    const float* b3  = (const float*)d_in[8];
    float* out = (float*)d_out;

    const int* row = ei;        // source
    const int* col = ei + E;    // target

    // workspace layout (all offsets 256B-aligned); total ~64.3 MB
    char* ws = (char*)d_ws;
    size_t off = 0;
    auto alloc = [&](size_t bytes) {
        void* p = ws + off;
        off += (bytes + 255) & ~(size_t)255;
        return p;
    };
    float* deg     = (float*)alloc((size_t)N * 4);
    float* dinv    = (float*)alloc((size_t)N * 4);
    int*   counts  = (int*)alloc((size_t)N * 4);
    int*   cursor  = (int*)alloc((size_t)N * 4);
    int*   col_ptr = (int*)alloc((size_t)(N + 1) * 4);
    int*   csr_src = (int*)alloc((size_t)E * 4);
    float* csr_w   = (float*)alloc((size_t)E * 4);
    float* bufA    = (float*)alloc((size_t)N * 768 * 4);   // XW buffer
    float* bufB    = (float*)alloc((size_t)N * 768 * 4);   // H buffer
    (void)ws_size;

    int nb_nodes = (N + 255) / 256;
    int nb_edges = (E + 255) / 256;

    // --- graph preprocessing (once; shared by all 3 layers) ---
    init_kernel<<<nb_nodes, 256, 0, stream>>>(deg, counts, cursor, N);
    deg_count_kernel<<<nb_edges, 256, 0, stream>>>(col, ew, deg, counts, E);
    scan_kernel<<<1, 1024, 0, stream>>>(counts, col_ptr, N);
    dinv_kernel<<<nb_nodes, 256, 0, stream>>>(deg, dinv, N);
    scatter_kernel<<<nb_edges, 256, 0, stream>>>(row, col, ew, dinv, col_ptr, cursor,
                                                 csr_src, csr_w, E);

    // --- layer 1: 256 -> 512, relu ---
    {
        const int K = 256, Nf = 512;
        dim3 grid(Nf / 64, (N + 63) / 64);
        gemm64_kernel<<<grid, 256, 0, stream>>>(x, W1, bufA, N, K, Nf);
        dim3 agrid(N, Nf / 256);
        agg_kernel<<<agrid, 64, 0, stream>>>(bufA, col_ptr, csr_src, csr_w, dinv, b1,
                                             bufB, Nf, 1);
    }
    // --- layer 2: 512 -> 768, relu ---
    {
        const int K = 512, Nf = 768;
        dim3 grid(Nf / 64, (N + 63) / 64);
        gemm64_kernel<<<grid, 256, 0, stream>>>(bufB, W2, bufA, N, K, Nf);
        dim3 agrid(N, Nf / 256);
        agg_kernel<<<agrid, 64, 0, stream>>>(bufA, col_ptr, csr_src, csr_w, dinv, b2,
                                             bufB, Nf, 1);
    }
    // --- layer 3: 768 -> 8, no relu ---
    {
        const int K = 768;
        gemm_n8_kernel<<<N, 64, 0, stream>>>(bufB, W3, bufA, K);
        agg8_kernel<<<N, 64, 0, stream>>>(bufA, col_ptr, csr_src, csr_w, dinv, b3, out);
    }
    (void)out_size; (void)n_in; (void)in_sizes;
}

// Round 2
// 434.940 us; speedup vs baseline: 1.2641x; 1.2641x over previous
//
#include <hip/hip_runtime.h>

#define N_NODES 10000
#define N_EDGES 320000

// ---------------------------------------------------------------------------
// Graph preprocessing: deg/dinv + CSR-by-destination build
// ---------------------------------------------------------------------------

__global__ __launch_bounds__(256) void init_kernel(float* deg, int* counts, int* cursor, int n) {
    int i = blockIdx.x * 256 + threadIdx.x;
    if (i < n) { deg[i] = 1.0f; counts[i] = 0; cursor[i] = 0; }  // self-loop weight 1
}

__global__ __launch_bounds__(256) void deg_count_kernel(const int* __restrict__ col,
                                                        const float* __restrict__ ew,
                                                        float* __restrict__ deg,
                                                        int* __restrict__ counts, int e) {
    int i = blockIdx.x * 256 + threadIdx.x;
    if (i < e) {
        int c = col[i];
        atomicAdd(deg + c, ew[i]);
        atomicAdd(counts + c, 1);
    }
}

// Single-block 1024-thread exclusive scan, shuffle-based (4 barriers/chunk).
__global__ __launch_bounds__(1024) void scan_kernel(const int* __restrict__ counts,
                                                    int* __restrict__ ptr, int n) {
    __shared__ int wsum[16];
    __shared__ int woff[16];
    __shared__ int carry_s, tot_s;
    const int lane = threadIdx.x & 63;
    const int wid = threadIdx.x >> 6;
    if (threadIdx.x == 0) carry_s = 0;
    __syncthreads();
    for (int base = 0; base < n; base += 1024) {
        int i = base + (int)threadIdx.x;
        int v = (i < n) ? counts[i] : 0;
        int x = v;  // wave-inclusive scan
#pragma unroll
        for (int off = 1; off < 64; off <<= 1) {
            int t = __shfl_up(x, off);
            if (lane >= off) x += t;
        }
        if (lane == 63) wsum[wid] = x;
        __syncthreads();                                    // B1
        if (wid == 0) {
            int s = (lane < 16) ? wsum[lane] : 0;
            int y = s;
#pragma unroll
            for (int off = 1; off < 16; off <<= 1) {
                int t = __shfl_up(y, off);
                if (lane >= off) y += t;
            }
            if (lane < 16) woff[lane] = y - s;              // exclusive wave offsets
            if (lane == 15) tot_s = y;                      // chunk total
        }
        __syncthreads();                                    // B2
        int carry = carry_s;
        if (i < n) ptr[i] = carry + woff[wid] + x - v;      // exclusive
        __syncthreads();                                    // B3
        if (threadIdx.x == 0) carry_s = carry + tot_s;
        __syncthreads();                                    // B4
    }
    if (threadIdx.x == 0) ptr[n] = carry_s;
}

__global__ __launch_bounds__(256) void dinv_kernel(const float* __restrict__ deg,
                                                   float* __restrict__ dinv, int n) {
    int i = blockIdx.x * 256 + threadIdx.x;
    if (i < n) {
        float d = deg[i];
        dinv[i] = (d > 0.0f) ? rsqrtf(d) : 0.0f;
    }
}

__global__ __launch_bounds__(256) void scatter_kernel(const int* __restrict__ row,
                                                      const int* __restrict__ col,
                                                      const float* __restrict__ ew,
                                                      const float* __restrict__ dinv,
                                                      const int* __restrict__ ptr,
                                                      int* __restrict__ cursor,
                                                      int* __restrict__ csr_src,
                                                      float* __restrict__ csr_w, int e) {
    int i = blockIdx.x * 256 + threadIdx.x;
    if (i < e) {
        int c = col[i], r = row[i];
        int pos = ptr[c] + atomicAdd(cursor + c, 1);
        csr_src[pos] = r;
        csr_w[pos] = dinv[r] * ew[i] * dinv[c];
    }
}

// ---------------------------------------------------------------------------
// Aggregation (pre-GEMM): out[n] = dinv[n]^2 * x[n] + sum_in w * x[src]
// One block per node, F/4 threads, float4/thread, edge loop unrolled x4.
// ---------------------------------------------------------------------------

__global__ __launch_bounds__(128) void agg_pre_kernel(const float* __restrict__ x,
                                                      const int* __restrict__ ptr,
                                                      const int* __restrict__ csr_src,
                                                      const float* __restrict__ csr_w,
                                                      const float* __restrict__ dinv,
                                                      float* __restrict__ out, int F) {
    const int node = blockIdx.x;
    const int f0 = (int)threadIdx.x * 4;
    const float di = dinv[node];
    const float si = di * di;
    float4 v = *(const float4*)(x + (size_t)node * F + f0);
    float ax = si * v.x, ay = si * v.y, az = si * v.z, aw = si * v.w;
    const int s = ptr[node], e = ptr[node + 1];
    int j = s;
    for (; j + 4 <= e; j += 4) {
        int s0 = csr_src[j], s1 = csr_src[j + 1], s2 = csr_src[j + 2], s3 = csr_src[j + 3];
        float w0 = csr_w[j], w1 = csr_w[j + 1], w2 = csr_w[j + 2], w3 = csr_w[j + 3];
        float4 g0 = *(const float4*)(x + (size_t)s0 * F + f0);
        float4 g1 = *(const float4*)(x + (size_t)s1 * F + f0);
        float4 g2 = *(const float4*)(x + (size_t)s2 * F + f0);
        float4 g3 = *(const float4*)(x + (size_t)s3 * F + f0);
        ax += w0 * g0.x + w1 * g1.x + w2 * g2.x + w3 * g3.x;
        ay += w0 * g0.y + w1 * g1.y + w2 * g2.y + w3 * g3.y;
        az += w0 * g0.z + w1 * g1.z + w2 * g2.z + w3 * g3.z;
        aw += w0 * g0.w + w1 * g1.w + w2 * g2.w + w3 * g3.w;
    }
    for (; j < e; ++j) {
        int sj = csr_src[j];
        float w = csr_w[j];
        float4 g = *(const float4*)(x + (size_t)sj * F + f0);
        ax += w * g.x; ay += w * g.y; az += w * g.z; aw += w * g.w;
    }
    float4 o = make_float4(ax, ay, az, aw);
    *(float4*)(out + (size_t)node * F + f0) = o;
}

// ---------------------------------------------------------------------------
// fp32 GEMM + bias (+relu): C[M,N] = A[M,K] @ B[K,N] + bias.
// 64x128 tile, 256 threads, 4x8 per thread, double-buffered LDS.
// Requires K % 16 == 0, N % 128 == 0.
// ---------------------------------------------------------------------------

__global__ __launch_bounds__(256) void gemm_bias_kernel(const float* __restrict__ A,
                                                        const float* __restrict__ B,
                                                        const float* __restrict__ bias,
                                                        float* __restrict__ C,
                                                        int M, int K, int N, int relu) {
    __shared__ float As[2][16][68];    // [k][m] transposed, stride 68 keeps 16B align + 2-way-only conflicts
    __shared__ float Bs[2][16][128];
    const int t = (int)threadIdx.x;
    const int bm = blockIdx.y * 64;
    const int bn = blockIdx.x * 128;
    const int tx = t & 15, ty = t >> 4;
    const int a_row = t >> 2, a_k = (t & 3) * 4;
    const int b_row = t >> 5, b_col = (t & 31) * 4;
    const bool a_valid = (bm + a_row) < M;
    const float* Ap = A + (size_t)(bm + a_row) * K + a_k;
    const float* Bp = B + (size_t)b_row * N + bn + b_col;

    float acc[4][8] = {};
    float4 ga, gb0, gb1;

    // prologue: tile 0
    ga = make_float4(0.f, 0.f, 0.f, 0.f);
    if (a_valid) ga = *(const float4*)(Ap);
    gb0 = *(const float4*)(Bp);
    gb1 = *(const float4*)(Bp + (size_t)8 * N);
    As[0][a_k + 0][a_row] = ga.x;
    As[0][a_k + 1][a_row] = ga.y;
    As[0][a_k + 2][a_row] = ga.z;
    As[0][a_k + 3][a_row] = ga.w;
    *(float4*)(&Bs[0][b_row][b_col]) = gb0;
    *(float4*)(&Bs[0][b_row + 8][b_col]) = gb1;
    __syncthreads();

    const int KT = K >> 4;
    for (int kt = 0; kt < KT; ++kt) {
        const int buf = kt & 1;
        if (kt + 1 < KT) {  // prefetch next tile into registers (hidden behind compute)
            const float* Ap2 = Ap + (kt + 1) * 16;
            ga = make_float4(0.f, 0.f, 0.f, 0.f);
            if (a_valid) ga = *(const float4*)(Ap2);
            const float* Bp2 = Bp + (size_t)(kt + 1) * 16 * N;
            gb0 = *(const float4*)(Bp2);
            gb1 = *(const float4*)(Bp2 + (size_t)8 * N);
        }
#pragma unroll
        for (int k = 0; k < 16; ++k) {
            float4 av = *(const float4*)(&As[buf][k][ty * 4]);
            float4 bv0 = *(const float4*)(&Bs[buf][k][tx * 4]);        // cols [tx*4, tx*4+3]
            float4 bv1 = *(const float4*)(&Bs[buf][k][64 + tx * 4]);   // cols [64+tx*4, ...]
            const float a4[4] = {av.x, av.y, av.z, av.w};
            const float b8[8] = {bv0.x, bv0.y, bv0.z, bv0.w, bv1.x, bv1.y, bv1.z, bv1.w};
#pragma unroll
            for (int i = 0; i < 4; ++i)
#pragma unroll
                for (int jj = 0; jj < 8; ++jj)
                    acc[i][jj] += a4[i] * b8[jj];
        }
        if (kt + 1 < KT) {
            const int nb = (kt + 1) & 1;
            As[nb][a_k + 0][a_row] = ga.x;
            As[nb][a_k + 1][a_row] = ga.y;
            As[nb][a_k + 2][a_row] = ga.z;
            As[nb][a_k + 3][a_row] = ga.w;
            *(float4*)(&Bs[nb][b_row][b_col]) = gb0;
            *(float4*)(&Bs[nb][b_row + 8][b_col]) = gb1;
        }
        __syncthreads();
    }

    // epilogue: bias (+relu), store
    float4 bb0 = *(const float4*)(bias + bn + tx * 4);
    float4 bb1 = *(const float4*)(bias + bn + 64 + tx * 4);
    const float bb[8] = {bb0.x, bb0.y, bb0.z, bb0.w, bb1.x, bb1.y, bb1.z, bb1.w};
#pragma unroll
    for (int i = 0; i < 4; ++i) {
        int m = bm + ty * 4 + i;
        if (m >= M) continue;
        float o[8];
#pragma unroll
        for (int jj = 0; jj < 8; ++jj) {
            float vv = acc[i][jj] + bb[jj];
            o[jj] = relu ? fmaxf(vv, 0.f) : vv;
        }
        float4 o0 = make_float4(o[0], o[1], o[2], o[3]);
        float4 o1 = make_float4(o[4], o[5], o[6], o[7]);
        *(float4*)(C + (size_t)m * N + bn + tx * 4) = o0;
        *(float4*)(C + (size_t)m * N + bn + 64 + tx * 4) = o1;
    }
}

// GEMM for layer 3: N=8, K=768.  One 64-lane wave per output row, no bias.
__global__ __launch_bounds__(64) void gemm_n8_kernel(const float* __restrict__ A,
                                                     const float* __restrict__ B,
                                                     float* __restrict__ C, int K) {
    int m = blockIdx.x;
    int lane = threadIdx.x;
    const float* a = A + (size_t)m * K;
    float acc[8] = {};
    for (int k = lane; k < K; k += 64) {
        float av = a[k];
        float4 b0 = *(const float4*)(B + (size_t)k * 8);
        float4 b1 = *(const float4*)(B + (size_t)k * 8 + 4);
        acc[0] += av * b0.x; acc[1] += av * b0.y; acc[2] += av * b0.z; acc[3] += av * b0.w;
        acc[4] += av * b1.x; acc[5] += av * b1.y; acc[6] += av * b1.z; acc[7] += av * b1.w;
    }
#pragma unroll
    for (int off = 32; off > 0; off >>= 1) {
#pragma unroll
        for (int i = 0; i < 8; ++i) acc[i] += __shfl_down(acc[i], off);
    }
    if (lane == 0) {
#pragma unroll
        for (int i = 0; i < 8; ++i) C[(size_t)m * 8 + i] = acc[i];
    }
}

// Aggregation for fout=8 (final layer, +bias): one wave per node, lanes split edges.
__global__ __launch_bounds__(64) void agg8_kernel(const float* __restrict__ xw,
                                                  const int* __restrict__ ptr,
                                                  const int* __restrict__ csr_src,
                                                  const float* __restrict__ csr_w,
                                                  const float* __restrict__ dinv,
                                                  const float* __restrict__ bias,
                                                  float* __restrict__ out) {
    int node = blockIdx.x;
    int lane = threadIdx.x;
    float acc[8] = {};
    int s = ptr[node], e = ptr[node + 1];
    for (int j = s + lane; j < e; j += 64) {
        int src = csr_src[j];
        float w = csr_w[j];
        float4 g0 = *(const float4*)(xw + (size_t)src * 8);
        float4 g1 = *(const float4*)(xw + (size_t)src * 8 + 4);
        acc[0] += w * g0.x; acc[1] += w * g0.y; acc[2] += w * g0.z; acc[3] += w * g0.w;
        acc[4] += w * g1.x; acc[5] += w * g1.y; acc[6] += w * g1.z; acc[7] += w * g1.w;
    }
#pragma unroll
    for (int off = 32; off > 0; off >>= 1) {
#pragma unroll
        for (int i = 0; i < 8; ++i) acc[i] += __shfl_down(acc[i], off);
    }
    if (lane == 0) {
        float di = dinv[node];
        float si = di * di;
#pragma unroll
        for (int i = 0; i < 8; ++i)
            out[(size_t)node * 8 + i] = acc[i] + si * xw[(size_t)node * 8 + i] + bias[i];
    }
}

// ---------------------------------------------------------------------------

extern "C" void kernel_launch(void* const* d_in, const int* in_sizes, int n_in,
                              void* d_out, int out_size, void* d_ws, size_t ws_size,
                              hipStream_t stream) {
    const int N = N_NODES, E = N_EDGES;
    const float* x   = (const float*)d_in[0];
    const int*   ei  = (const int*)d_in[1];   // [2, E] (row=source, col=target)
    const float* ew  = (const float*)d_in[2];
    const float* W1  = (const float*)d_in[3];
    const float* b1  = (const float*)d_in[4];
    const float* W2  = (const float*)d_in[5];
    const float* b2  = (const float*)d_in[6];
    const float* W3  = (const float*)d_in[7];
    const float* b3  = (const float*)d_in[8];
    float* out = (float*)d_out;

    const int* row = ei;        // source
    const int* col = ei + E;    // target

    // workspace layout (256B-aligned); ~64 MB
    char* ws = (char*)d_ws;
    size_t off = 0;
    auto alloc = [&](size_t bytes) {
        void* p = ws + off;
        off += (bytes + 255) & ~(size_t)255;
        return p;
    };
    float* deg     = (float*)alloc((size_t)N * 4);
    float* dinv    = (float*)alloc((size_t)N * 4);
    int*   counts  = (int*)alloc((size_t)N * 4);
    int*   cursor  = (int*)alloc((size_t)N * 4);
    int*   col_ptr = (int*)alloc((size_t)(N + 1) * 4);
    int*   csr_src = (int*)alloc((size_t)E * 4);
    float* csr_w   = (float*)alloc((size_t)E * 4);
    float* bufA    = (float*)alloc((size_t)N * 768 * 4);
    float* bufB    = (float*)alloc((size_t)N * 768 * 4);
    (void)ws_size;

    int nb_nodes = (N + 255) / 256;
    int nb_edges = (E + 255) / 256;

    // --- graph preprocessing (once; shared by all 3 layers) ---
    init_kernel<<<nb_nodes, 256, 0, stream>>>(deg, counts, cursor, N);
    deg_count_kernel<<<nb_edges, 256, 0, stream>>>(col, ew, deg, counts, E);
    scan_kernel<<<1, 1024, 0, stream>>>(counts, col_ptr, N);
    dinv_kernel<<<nb_nodes, 256, 0, stream>>>(deg, dinv, N);
    scatter_kernel<<<nb_edges, 256, 0, stream>>>(row, col, ew, dinv, col_ptr, cursor,
                                                 csr_src, csr_w, E);

    // --- layer 1: agg(256) -> gemm 256->512 (+b1, relu) ---
    agg_pre_kernel<<<N, 64, 0, stream>>>(x, col_ptr, csr_src, csr_w, dinv, bufA, 256);
    {
        dim3 grid(512 / 128, (N + 63) / 64);
        gemm_bias_kernel<<<grid, 256, 0, stream>>>(bufA, W1, b1, bufB, N, 256, 512, 1);
    }
    // --- layer 2: agg(512) -> gemm 512->768 (+b2, relu) ---
    agg_pre_kernel<<<N, 128, 0, stream>>>(bufB, col_ptr, csr_src, csr_w, dinv, bufA, 512);
    {
        dim3 grid(768 / 128, (N + 63) / 64);
        gemm_bias_kernel<<<grid, 256, 0, stream>>>(bufA, W2, b2, bufB, N, 512, 768, 1);
    }
    // --- layer 3: gemm 768->8 -> agg8 (+b3) ---
    gemm_n8_kernel<<<N, 64, 0, stream>>>(bufB, W3, bufA, 768);
    agg8_kernel<<<N, 64, 0, stream>>>(bufA, col_ptr, csr_src, csr_w, dinv, b3, out);

    (void)out_size; (void)n_in; (void)in_sizes;
}